// Round 4
// baseline (389.390 us; speedup 1.0000x reference)
//
#include <hip/hip_runtime.h>
#include <math.h>

// Problem constants (reference: B=2, L=19, H=800, W=640, R1=R2=41)
#define NB 2
#define NL 19
#define NH 800
#define NW 640
#define NHW (NH * NW)
#define NMAPS (NB * NL)          // 38
#define R1I 41
#define R1SQ 1681.0f
#define INV_R2 (1.0f / 41.0f)

// Single plain launch (no cooperative):
//   blocks [0, DENSE_BLOCKS)          : dense softplus sum, 64 blocks/map
//   blocks [DENSE_BLOCKS, TOTAL)      : disk sums, 16 blocks/map
// Last-finished block (atomic counter) finalizes -> out[0].
#define SUB_DENSE 64
#define SUB_DISK  16
#define DENSE_BLOCKS (NMAPS * SUB_DENSE)   // 2432
#define DISK_BLOCKS  (NMAPS * SUB_DISK)    // 608
#define TOTAL_BLOCKS (DENSE_BLOCKS + DISK_BLOCKS)  // 3040

// ws layout (floats), all partial slots written unconditionally:
//   [m*SUB_DENSE + sub]                          dense partials (2432)
//   [WS_DISK_BASE + (m*SUB_DISK + sub)*4 + k]    disk partials sx,slx,sly,cnt
//   [WS_CNT_IDX] (as uint)                       completion counter
#define WS_DISK_BASE DENSE_BLOCKS                       // 2432
#define WS_CNT_IDX   (WS_DISK_BASE + DISK_BLOCKS * 4)   // 4864
#define POISON_U 0xAAAAAAAAu

__device__ __forceinline__ float softplus_part(float x) {
    // max(x,0) + log1p(exp(-|x|)); fast-math variant, rel err ~1e-6
    return fmaxf(x, 0.0f) + __logf(1.0f + __expf(-fabsf(x)));
}

__global__ __launch_bounds__(256) void fused_all_kernel(
        const float* __restrict__ fm, const float* __restrict__ lm,
        float* __restrict__ ws, float* __restrict__ out) {
    const int blk = blockIdx.x;
    __shared__ float sm[4 * 4];
    __shared__ int last_flag;

    if (blk < DENSE_BLOCKS) {
        // ---- dense softplus over logits channel of map m ----
        const int m = blk / SUB_DENSE, sub = blk % SUB_DENSE;
        const int b = m / NL, c = m % NL;
        const float4* __restrict__ base =
            (const float4*)(fm + (size_t)(b * 3 * NL + c) * NHW);
        const int n4 = NHW / 4;                       // 128000
        float s = 0.0f;
        const int stride = SUB_DENSE * 256;           // 16384
        for (int i = sub * 256 + threadIdx.x; i < n4; i += stride) {
            float4 v = base[i];
            s += softplus_part(v.x);
            s += softplus_part(v.y);
            s += softplus_part(v.z);
            s += softplus_part(v.w);
        }
        #pragma unroll
        for (int o = 32; o > 0; o >>= 1) s += __shfl_down(s, o, 64);
        if ((threadIdx.x & 63) == 0) sm[threadIdx.x >> 6] = s;
        __syncthreads();
        if (threadIdx.x == 0)
            ws[m * SUB_DENSE + sub] = sm[0] + sm[1] + sm[2] + sm[3];
    } else {
        // ---- disk sums over the <=83x83 bounding box of map m ----
        const int d = blk - DENSE_BLOCKS;
        const int m = d / SUB_DISK, sub = d % SUB_DISK;
        const int b = m / NL, c = m % NL;
        const float X = rintf(lm[(b * NL + c) * 2 + 0] * (float)(NH - 1));
        const float Y = rintf(lm[(b * NL + c) * 2 + 1] * (float)(NW - 1));
        const int Xi = (int)X, Yi = (int)Y;
        const int i0 = max(0, Xi - R1I), i1 = min(NH - 1, Xi + R1I);
        const int j0 = max(0, Yi - R1I), j1 = min(NW - 1, Yi + R1I);
        const int ni = i1 - i0 + 1, nj = j1 - j0 + 1;
        const int tot = ni * nj;

        const float* __restrict__ logit = fm + (size_t)(b * 3 * NL + c) * NHW;
        const float* __restrict__ px = logit + (size_t)NL * NHW;
        const float* __restrict__ py = px + (size_t)NL * NHW;

        float sx = 0.f, slx = 0.f, sly = 0.f, cnt = 0.f;
        for (int idx = sub * 256 + threadIdx.x; idx < tot;
             idx += SUB_DISK * 256) {
            const int i = i0 + idx / nj;
            const int j = j0 + idx % nj;
            const float dx = X - (float)i;
            const float dy = Y - (float)j;
            if (dx * dx + dy * dy <= R1SQ) {
                const size_t o = (size_t)i * NW + j;
                sx  += logit[o];
                slx += fabsf(px[o] - dx * INV_R2);
                sly += fabsf(py[o] - dy * INV_R2);
                cnt += 1.0f;
            }
        }
        #pragma unroll
        for (int o = 32; o > 0; o >>= 1) {
            sx  += __shfl_down(sx, o, 64);
            slx += __shfl_down(slx, o, 64);
            sly += __shfl_down(sly, o, 64);
            cnt += __shfl_down(cnt, o, 64);
        }
        const int w = threadIdx.x >> 6;
        if ((threadIdx.x & 63) == 0) {
            sm[w * 4 + 0] = sx; sm[w * 4 + 1] = slx;
            sm[w * 4 + 2] = sly; sm[w * 4 + 3] = cnt;
        }
        __syncthreads();
        if (threadIdx.x == 0) {
            float4 r;
            r.x = sm[0] + sm[4] + sm[8]  + sm[12];
            r.y = sm[1] + sm[5] + sm[9]  + sm[13];
            r.z = sm[2] + sm[6] + sm[10] + sm[14];
            r.w = sm[3] + sm[7] + sm[11] + sm[15];
            ((float4*)(ws + WS_DISK_BASE))[m * SUB_DISK + sub] = r;
        }
    }

    // ---- last-block-done detection (init-tolerant: poison 0xAA.. or zero) ----
    if (threadIdx.x == 0) {
        __threadfence();   // agent-scope release: partials visible device-wide
        unsigned old = atomicAdd((unsigned*)(ws + WS_CNT_IDX), 1u);
        last_flag = (old == POISON_U + (unsigned)(TOTAL_BLOCKS - 1)) ||
                    (old == (unsigned)(TOTAL_BLOCKS - 1));
    }
    __syncthreads();

    if (last_flag) {
        __threadfence();   // acquire: invalidate caches before reading partials
        __shared__ float cat[5][NMAPS];
        __shared__ float vm[NMAPS];
        const int t = threadIdx.x;
        if (t < 5 * NMAPS) {                       // 190 < 256
            const int ci = t / NMAPS, m = t % NMAPS;
            float s = 0.0f;
            if (ci == 0) {
                #pragma unroll 8
                for (int i = 0; i < SUB_DENSE; ++i) s += ws[m * SUB_DENSE + i];
            } else {
                const int k = ci - 1;
                #pragma unroll 8
                for (int i = 0; i < SUB_DISK; ++i)
                    s += ws[WS_DISK_BASE + (m * SUB_DISK + i) * 4 + k];
            }
            cat[ci][m] = s;
        }
        __syncthreads();
        if (t < NMAPS) {
            vm[t] = 2.0f * (cat[0][t] - cat[1][t]) / (float)NHW
                  + (cat[2][t] + cat[3][t]) / cat[4][t];
        }
        __syncthreads();
        if (t == 0) {
            float v = 0.0f;
            #pragma unroll
            for (int m = 0; m < NMAPS; ++m) v += vm[m];
            out[0] = v / (float)NMAPS;
        }
    }
}

extern "C" void kernel_launch(void* const* d_in, const int* in_sizes, int n_in,
                              void* d_out, int out_size, void* d_ws, size_t ws_size,
                              hipStream_t stream) {
    const float* fm = (const float*)d_in[0];   // (2, 57, 800, 640) fp32
    const float* lm = (const float*)d_in[1];   // (2, 19, 2) fp32
    float* out = (float*)d_out;                // scalar fp32
    float* ws  = (float*)d_ws;

    fused_all_kernel<<<TOTAL_BLOCKS, 256, 0, stream>>>(fm, lm, ws, out);
}

// Round 5
// 389.228 us; speedup vs baseline: 1.0004x; 1.0004x over previous
//
#include <hip/hip_runtime.h>
#include <math.h>

// Problem constants (reference: B=2, L=19, H=800, W=640, R1=R2=41)
#define NB 2
#define NL 19
#define NH 800
#define NW 640
#define NHW (NH * NW)
#define NMAPS (NB * NL)          // 38
#define R1I 41
#define R1SQ 1681.0f
#define INV_R2 (1.0f / 41.0f)

// Single plain launch, last-block-done finalize.
// Cross-XCD visibility via fine-grained agent-scope atomics (global_store sc1
// write-through to LLC) — NOT __threadfence(): the fence compiles to
// buffer_wbl2 (full per-XCD L2 writeback) per block, which cost +140us in R4.
#define SUB_DENSE 64
#define SUB_DISK  16
#define DENSE_BLOCKS (NMAPS * SUB_DENSE)   // 2432
#define DISK_BLOCKS  (NMAPS * SUB_DISK)    // 608
#define TOTAL_BLOCKS (DENSE_BLOCKS + DISK_BLOCKS)  // 3040

// ws layout (floats), all partial slots written unconditionally:
//   [m*SUB_DENSE + sub]                          dense partials (2432)
//   [WS_DISK_BASE + (m*SUB_DISK + sub)*4 + k]    disk partials sx,slx,sly,cnt
//   [WS_CNT_IDX] (as uint)                       completion counter
#define WS_DISK_BASE DENSE_BLOCKS                       // 2432
#define WS_CNT_IDX   (WS_DISK_BASE + DISK_BLOCKS * 4)   // 4864
#define POISON_U 0xAAAAAAAAu

__device__ __forceinline__ float softplus_part(float x) {
    // max(x,0) + log1p(exp(-|x|)); fast-math variant, rel err ~1e-6
    return fmaxf(x, 0.0f) + __logf(1.0f + __expf(-fabsf(x)));
}

__device__ __forceinline__ void agent_store(float* p, float v) {
    __hip_atomic_store(p, v, __ATOMIC_RELAXED, __HIP_MEMORY_SCOPE_AGENT);
}
__device__ __forceinline__ float agent_load(const float* p) {
    return __hip_atomic_load(p, __ATOMIC_RELAXED, __HIP_MEMORY_SCOPE_AGENT);
}

__global__ __launch_bounds__(256) void fused_all_kernel(
        const float* __restrict__ fm, const float* __restrict__ lm,
        float* __restrict__ ws, float* __restrict__ out) {
    const int blk = blockIdx.x;
    __shared__ float sm[4 * 4];
    __shared__ int last_flag;

    if (blk < DENSE_BLOCKS) {
        // ---- dense softplus over logits channel of map m ----
        const int m = blk / SUB_DENSE, sub = blk % SUB_DENSE;
        const int b = m / NL, c = m % NL;
        const float4* __restrict__ base =
            (const float4*)(fm + (size_t)(b * 3 * NL + c) * NHW);
        const int n4 = NHW / 4;                       // 128000
        float s = 0.0f;
        const int stride = SUB_DENSE * 256;           // 16384
        for (int i = sub * 256 + threadIdx.x; i < n4; i += stride) {
            float4 v = base[i];
            s += softplus_part(v.x);
            s += softplus_part(v.y);
            s += softplus_part(v.z);
            s += softplus_part(v.w);
        }
        #pragma unroll
        for (int o = 32; o > 0; o >>= 1) s += __shfl_down(s, o, 64);
        if ((threadIdx.x & 63) == 0) sm[threadIdx.x >> 6] = s;
        __syncthreads();
        if (threadIdx.x == 0)
            agent_store(&ws[m * SUB_DENSE + sub], sm[0] + sm[1] + sm[2] + sm[3]);
    } else {
        // ---- disk sums over the <=83x83 bounding box of map m ----
        const int d = blk - DENSE_BLOCKS;
        const int m = d / SUB_DISK, sub = d % SUB_DISK;
        const int b = m / NL, c = m % NL;
        const float X = rintf(lm[(b * NL + c) * 2 + 0] * (float)(NH - 1));
        const float Y = rintf(lm[(b * NL + c) * 2 + 1] * (float)(NW - 1));
        const int Xi = (int)X, Yi = (int)Y;
        const int i0 = max(0, Xi - R1I), i1 = min(NH - 1, Xi + R1I);
        const int j0 = max(0, Yi - R1I), j1 = min(NW - 1, Yi + R1I);
        const int ni = i1 - i0 + 1, nj = j1 - j0 + 1;
        const int tot = ni * nj;

        const float* __restrict__ logit = fm + (size_t)(b * 3 * NL + c) * NHW;
        const float* __restrict__ px = logit + (size_t)NL * NHW;
        const float* __restrict__ py = px + (size_t)NL * NHW;

        float sx = 0.f, slx = 0.f, sly = 0.f, cnt = 0.f;
        for (int idx = sub * 256 + threadIdx.x; idx < tot;
             idx += SUB_DISK * 256) {
            const int i = i0 + idx / nj;
            const int j = j0 + idx % nj;
            const float dx = X - (float)i;
            const float dy = Y - (float)j;
            if (dx * dx + dy * dy <= R1SQ) {
                const size_t o = (size_t)i * NW + j;
                sx  += logit[o];
                slx += fabsf(px[o] - dx * INV_R2);
                sly += fabsf(py[o] - dy * INV_R2);
                cnt += 1.0f;
            }
        }
        #pragma unroll
        for (int o = 32; o > 0; o >>= 1) {
            sx  += __shfl_down(sx, o, 64);
            slx += __shfl_down(slx, o, 64);
            sly += __shfl_down(sly, o, 64);
            cnt += __shfl_down(cnt, o, 64);
        }
        const int w = threadIdx.x >> 6;
        if ((threadIdx.x & 63) == 0) {
            sm[w * 4 + 0] = sx; sm[w * 4 + 1] = slx;
            sm[w * 4 + 2] = sly; sm[w * 4 + 3] = cnt;
        }
        __syncthreads();
        if (threadIdx.x == 0) {
            float* p = ws + WS_DISK_BASE + (m * SUB_DISK + sub) * 4;
            agent_store(p + 0, sm[0] + sm[4] + sm[8]  + sm[12]);
            agent_store(p + 1, sm[1] + sm[5] + sm[9]  + sm[13]);
            agent_store(p + 2, sm[2] + sm[6] + sm[10] + sm[14]);
            agent_store(p + 3, sm[3] + sm[7] + sm[11] + sm[15]);
        }
    }

    // ---- last-block-done detection (init-tolerant: poison 0xAA.. or zero).
    // ACQ_REL agent-scope RMW: orders this block's sc1 partial stores (release)
    // and makes all earlier blocks' partials visible to the last one (acquire).
    if (threadIdx.x == 0) {
        unsigned old = __hip_atomic_fetch_add(
            (unsigned*)(ws + WS_CNT_IDX), 1u,
            __ATOMIC_ACQ_REL, __HIP_MEMORY_SCOPE_AGENT);
        last_flag = (old == POISON_U + (unsigned)(TOTAL_BLOCKS - 1)) ||
                    (old == (unsigned)(TOTAL_BLOCKS - 1));
    }
    __syncthreads();

    if (last_flag) {
        __shared__ float cat[5][NMAPS];
        __shared__ float vm[NMAPS];
        const int t = threadIdx.x;
        if (t < 5 * NMAPS) {                       // 190 < 256
            const int ci = t / NMAPS, m = t % NMAPS;
            float s = 0.0f;
            if (ci == 0) {
                #pragma unroll 8
                for (int i = 0; i < SUB_DENSE; ++i)
                    s += agent_load(&ws[m * SUB_DENSE + i]);
            } else {
                const int k = ci - 1;
                #pragma unroll 8
                for (int i = 0; i < SUB_DISK; ++i)
                    s += agent_load(&ws[WS_DISK_BASE + (m * SUB_DISK + i) * 4 + k]);
            }
            cat[ci][m] = s;
        }
        __syncthreads();
        if (t < NMAPS) {
            vm[t] = 2.0f * (cat[0][t] - cat[1][t]) / (float)NHW
                  + (cat[2][t] + cat[3][t]) / cat[4][t];
        }
        __syncthreads();
        if (t == 0) {
            float v = 0.0f;
            #pragma unroll
            for (int m = 0; m < NMAPS; ++m) v += vm[m];
            out[0] = v / (float)NMAPS;
        }
    }
}

extern "C" void kernel_launch(void* const* d_in, const int* in_sizes, int n_in,
                              void* d_out, int out_size, void* d_ws, size_t ws_size,
                              hipStream_t stream) {
    const float* fm = (const float*)d_in[0];   // (2, 57, 800, 640) fp32
    const float* lm = (const float*)d_in[1];   // (2, 19, 2) fp32
    float* out = (float*)d_out;                // scalar fp32
    float* ws  = (float*)d_ws;

    fused_all_kernel<<<TOTAL_BLOCKS, 256, 0, stream>>>(fm, lm, ws, out);
}

// Round 6
// 302.078 us; speedup vs baseline: 1.2890x; 1.2885x over previous
//
#include <hip/hip_runtime.h>
#include <math.h>

// Problem constants (reference: B=2, L=19, H=800, W=640, R1=R2=41)
#define NB 2
#define NL 19
#define NH 800
#define NW 640
#define NHW (NH * NW)
#define NMAPS (NB * NL)          // 38
#define R1I 41
#define R1SQ 1681.0f
#define INV_R2 (1.0f / 41.0f)

// Single plain launch, last-block-done finalize.
// NO cache-maintenance ops anywhere (R4's __threadfence and R5's ACQ_REL RMW
// both emitted buffer_wbl2/buffer_inv per block -> 153us fence storm).
// Visibility protocol: every cross-block word moves via agent-scope RELAXED
// atomics (sc1 write-through/bypass to the coherent LLC); ordering via an
// explicit s_waitcnt vmcnt(0) in thread 0 before the counter bump.
#define SUB_DENSE 64
#define SUB_DISK  16
#define DENSE_BLOCKS (NMAPS * SUB_DENSE)   // 2432
#define DISK_BLOCKS  (NMAPS * SUB_DISK)    // 608
#define TOTAL_BLOCKS (DENSE_BLOCKS + DISK_BLOCKS)  // 3040

// ws layout (floats), all partial slots written unconditionally:
//   [m*SUB_DENSE + sub]                          dense partials (2432)
//   [WS_DISK_BASE + (m*SUB_DISK + sub)*4 + k]    disk partials sx,slx,sly,cnt
//   [WS_CNT_IDX] (as uint)                       completion counter
#define WS_DISK_BASE DENSE_BLOCKS                       // 2432
#define WS_CNT_IDX   (WS_DISK_BASE + DISK_BLOCKS * 4)   // 4864
#define POISON_U 0xAAAAAAAAu

__device__ __forceinline__ float softplus_part(float x) {
    // max(x,0) + log1p(exp(-|x|)); fast-math variant, rel err ~1e-6
    return fmaxf(x, 0.0f) + __logf(1.0f + __expf(-fabsf(x)));
}

__device__ __forceinline__ void agent_store(float* p, float v) {
    __hip_atomic_store(p, v, __ATOMIC_RELAXED, __HIP_MEMORY_SCOPE_AGENT);
}
__device__ __forceinline__ float agent_load(const float* p) {
    return __hip_atomic_load(p, __ATOMIC_RELAXED, __HIP_MEMORY_SCOPE_AGENT);
}

__global__ __launch_bounds__(256) void fused_all_kernel(
        const float* __restrict__ fm, const float* __restrict__ lm,
        float* __restrict__ ws, float* __restrict__ out) {
    const int blk = blockIdx.x;
    __shared__ float sm[4 * 4];
    __shared__ int last_flag;

    if (blk < DENSE_BLOCKS) {
        // ---- dense softplus over logits channel of map m ----
        const int m = blk / SUB_DENSE, sub = blk % SUB_DENSE;
        const int b = m / NL, c = m % NL;
        const float4* __restrict__ base =
            (const float4*)(fm + (size_t)(b * 3 * NL + c) * NHW);
        const int n4 = NHW / 4;                       // 128000
        const int stride = SUB_DENSE * 256;           // 16384
        float s = 0.0f;
        int i = sub * 256 + threadIdx.x;
        // 2 independent loads per iteration for memory-level parallelism
        for (; i + stride < n4; i += 2 * stride) {
            float4 a = base[i];
            float4 b4 = base[i + stride];
            s += softplus_part(a.x) + softplus_part(a.y)
               + softplus_part(a.z) + softplus_part(a.w);
            s += softplus_part(b4.x) + softplus_part(b4.y)
               + softplus_part(b4.z) + softplus_part(b4.w);
        }
        for (; i < n4; i += stride) {
            float4 a = base[i];
            s += softplus_part(a.x) + softplus_part(a.y)
               + softplus_part(a.z) + softplus_part(a.w);
        }
        #pragma unroll
        for (int o = 32; o > 0; o >>= 1) s += __shfl_down(s, o, 64);
        if ((threadIdx.x & 63) == 0) sm[threadIdx.x >> 6] = s;
        __syncthreads();
        if (threadIdx.x == 0)
            agent_store(&ws[m * SUB_DENSE + sub], sm[0] + sm[1] + sm[2] + sm[3]);
    } else {
        // ---- disk sums over the <=83x83 bounding box of map m ----
        const int d = blk - DENSE_BLOCKS;
        const int m = d / SUB_DISK, sub = d % SUB_DISK;
        const int b = m / NL, c = m % NL;
        const float X = rintf(lm[(b * NL + c) * 2 + 0] * (float)(NH - 1));
        const float Y = rintf(lm[(b * NL + c) * 2 + 1] * (float)(NW - 1));
        const int Xi = (int)X, Yi = (int)Y;
        const int i0 = max(0, Xi - R1I), i1 = min(NH - 1, Xi + R1I);
        const int j0 = max(0, Yi - R1I), j1 = min(NW - 1, Yi + R1I);
        const int ni = i1 - i0 + 1, nj = j1 - j0 + 1;
        const int tot = ni * nj;

        const float* __restrict__ logit = fm + (size_t)(b * 3 * NL + c) * NHW;
        const float* __restrict__ px = logit + (size_t)NL * NHW;
        const float* __restrict__ py = px + (size_t)NL * NHW;

        float sx = 0.f, slx = 0.f, sly = 0.f, cnt = 0.f;
        for (int idx = sub * 256 + threadIdx.x; idx < tot;
             idx += SUB_DISK * 256) {
            const int i = i0 + idx / nj;
            const int j = j0 + idx % nj;
            const float dx = X - (float)i;
            const float dy = Y - (float)j;
            if (dx * dx + dy * dy <= R1SQ) {
                const size_t o = (size_t)i * NW + j;
                sx  += logit[o];
                slx += fabsf(px[o] - dx * INV_R2);
                sly += fabsf(py[o] - dy * INV_R2);
                cnt += 1.0f;
            }
        }
        #pragma unroll
        for (int o = 32; o > 0; o >>= 1) {
            sx  += __shfl_down(sx, o, 64);
            slx += __shfl_down(slx, o, 64);
            sly += __shfl_down(sly, o, 64);
            cnt += __shfl_down(cnt, o, 64);
        }
        const int w = threadIdx.x >> 6;
        if ((threadIdx.x & 63) == 0) {
            sm[w * 4 + 0] = sx; sm[w * 4 + 1] = slx;
            sm[w * 4 + 2] = sly; sm[w * 4 + 3] = cnt;
        }
        __syncthreads();
        if (threadIdx.x == 0) {
            float* p = ws + WS_DISK_BASE + (m * SUB_DISK + sub) * 4;
            agent_store(p + 0, sm[0] + sm[4] + sm[8]  + sm[12]);
            agent_store(p + 1, sm[1] + sm[5] + sm[9]  + sm[13]);
            agent_store(p + 2, sm[2] + sm[6] + sm[10] + sm[14]);
            agent_store(p + 3, sm[3] + sm[7] + sm[11] + sm[15]);
        }
    }

    // ---- last-block-done detection (init-tolerant: poison 0xAA.. or zero).
    // RELAXED RMW (no cache maintenance); hand-rolled "release": wait until
    // this thread's sc1 write-through partial stores reached the LLC.
    if (threadIdx.x == 0) {
        asm volatile("s_waitcnt vmcnt(0)" ::: "memory");
        unsigned old = __hip_atomic_fetch_add(
            (unsigned*)(ws + WS_CNT_IDX), 1u,
            __ATOMIC_RELAXED, __HIP_MEMORY_SCOPE_AGENT);
        last_flag = (old == POISON_U + (unsigned)(TOTAL_BLOCKS - 1)) ||
                    (old == (unsigned)(TOTAL_BLOCKS - 1));
    }
    __syncthreads();

    if (last_flag) {
        __shared__ float cat[5][NMAPS];
        __shared__ float vm[NMAPS];
        const int t = threadIdx.x;
        if (t < 5 * NMAPS) {                       // 190 < 256
            const int ci = t / NMAPS, m = t % NMAPS;
            float s = 0.0f;
            if (ci == 0) {
                #pragma unroll 8
                for (int i = 0; i < SUB_DENSE; ++i)
                    s += agent_load(&ws[m * SUB_DENSE + i]);
            } else {
                const int k = ci - 1;
                #pragma unroll 8
                for (int i = 0; i < SUB_DISK; ++i)
                    s += agent_load(&ws[WS_DISK_BASE + (m * SUB_DISK + i) * 4 + k]);
            }
            cat[ci][m] = s;
        }
        __syncthreads();
        if (t < NMAPS) {
            vm[t] = 2.0f * (cat[0][t] - cat[1][t]) / (float)NHW
                  + (cat[2][t] + cat[3][t]) / cat[4][t];
        }
        __syncthreads();
        if (t == 0) {
            float v = 0.0f;
            #pragma unroll
            for (int m = 0; m < NMAPS; ++m) v += vm[m];
            out[0] = v / (float)NMAPS;
        }
    }
}

extern "C" void kernel_launch(void* const* d_in, const int* in_sizes, int n_in,
                              void* d_out, int out_size, void* d_ws, size_t ws_size,
                              hipStream_t stream) {
    const float* fm = (const float*)d_in[0];   // (2, 57, 800, 640) fp32
    const float* lm = (const float*)d_in[1];   // (2, 19, 2) fp32
    float* out = (float*)d_out;                // scalar fp32
    float* ws  = (float*)d_ws;

    fused_all_kernel<<<TOTAL_BLOCKS, 256, 0, stream>>>(fm, lm, ws, out);
}